// Round 1
// 1267.999 us; speedup vs baseline: 1.2706x; 1.2706x over previous
//
#include <hip/hip_runtime.h>
#include <hip/hip_bf16.h>
#include <stdint.h>

// Int8SymmetricLinear: out[m,n] = sum_k x[m,k] * (int8 W[n,k]) * scale[n] + bias[n]
// M=8192 (B*S), K=4096, N=11008.
// Prepass: x -> bf16 (RTNE), W -> bf16 (exact, |W|<=127).
// Main GEMM: 256x256 8-phase template (m201/m204): BK=64, 8 waves (2Mx4N),
// 128 KiB LDS double-buffer, st_16x32 XOR swizzle (inverse-swizzled global src,
// swizzled ds_read), counted vmcnt(4) at phases 4/8 (never 0 in main loop),
// setprio(1) around MFMA clusters, bijective XCD block swizzle (1376 % 8 == 0).

#define M_DIM 8192
#define K_DIM 4096
#define N_DIM 11008

// fallback tile (register-staged path)
#define BM 128
#define BN 128
#define BK 32

// 8-phase tile
#define TBM 256
#define TBN 256
#define TBK 64

typedef __attribute__((ext_vector_type(8))) short short8;   // 8 bf16 = 4 VGPRs
typedef __attribute__((ext_vector_type(4))) float floatx4;

__device__ __forceinline__ unsigned short f2bf(float f) {
    __hip_bfloat16 h = __float2bfloat16(f);   // RTNE
    return __builtin_bit_cast(unsigned short, h);
}

// ---- prepass: x fp32 -> bf16 bits (8 elems/thread) ----
__global__ void cvt_x(const float* __restrict__ x, unsigned short* __restrict__ o) {
    int i = (blockIdx.x * 256 + threadIdx.x) * 8;
    float4 a = *(const float4*)(x + i);
    float4 b = *(const float4*)(x + i + 4);
    union { unsigned short h[8]; uint4 v; } u;
    u.h[0] = f2bf(a.x); u.h[1] = f2bf(a.y); u.h[2] = f2bf(a.z); u.h[3] = f2bf(a.w);
    u.h[4] = f2bf(b.x); u.h[5] = f2bf(b.y); u.h[6] = f2bf(b.z); u.h[7] = f2bf(b.w);
    *(uint4*)(o + i) = u.v;
}

// ---- prepass: W int32 (values in [-127,127]) -> bf16 bits (exact) ----
__global__ void cvt_w(const int* __restrict__ w, unsigned short* __restrict__ o) {
    int i = (blockIdx.x * 256 + threadIdx.x) * 8;
    int4 a = *(const int4*)(w + i);
    int4 b = *(const int4*)(w + i + 4);
    union { unsigned short h[8]; uint4 v; } u;
    u.h[0] = f2bf((float)a.x); u.h[1] = f2bf((float)a.y);
    u.h[2] = f2bf((float)a.z); u.h[3] = f2bf((float)a.w);
    u.h[4] = f2bf((float)b.x); u.h[5] = f2bf((float)b.y);
    u.h[6] = f2bf((float)b.z); u.h[7] = f2bf((float)b.w);
    *(uint4*)(o + i) = u.v;
}

// ================= 256x256 8-phase GEMM =================
// LDS layout per tile: 256 rows x 64 bf16 cols, row = 128 B.
// st_16x32 swizzle: stored_off = linear_off ^ (((linear_off>>9)&1)<<5).
// gload_lds writes linearly -> source address carries the inverse permutation.

#define BARX()  __builtin_amdgcn_s_barrier()
#define LGKM0() asm volatile("s_waitcnt lgkmcnt(0)" ::: "memory")
#define VM4()   asm volatile("s_waitcnt vmcnt(4)" ::: "memory")
#define PHI()   __builtin_amdgcn_s_setprio(1)
#define PLO()   __builtin_amdgcn_s_setprio(0)

// stage one half-tile (128 rows x 64 cols): 2 x global_load_lds dwordx4 per wave
#define STAGE(GP, LP)                                                              \
    do {                                                                           \
        __builtin_amdgcn_global_load_lds(                                          \
            (const __attribute__((address_space(1))) void*)((GP) + so0),           \
            (__attribute__((address_space(3))) void*)((LP) + tid * 8), 16, 0, 0);  \
        __builtin_amdgcn_global_load_lds(                                          \
            (const __attribute__((address_space(1))) void*)((GP) + so1),           \
            (__attribute__((address_space(3))) void*)((LP) + 4096 + tid * 8), 16, 0, 0); \
    } while (0)

// load 4 A-frags (rows MOFF..MOFF+3 of wave's 8) x 2 k-slices, swizzled ds_read
#define LDA4(BASE, MOFF)                                                           \
    do {                                                                           \
        _Pragma("unroll")                                                          \
        for (int m_ = 0; m_ < 4; ++m_)                                             \
            _Pragma("unroll")                                                      \
            for (int ks_ = 0; ks_ < 2; ++ks_)                                      \
                af[m_][ks_] = *(const short8*)((BASE) +                            \
                    ((wm * 128 + ((MOFF) + m_) * 16 + fr) * 128 +                  \
                     ((ks_ * 64 + fk16) ^ sxor)));                                 \
    } while (0)

// load 2 B-frags into bf[N0],bf[N0+1] x 2 k-slices
#define LDB2(BASE, N0)                                                             \
    do {                                                                           \
        _Pragma("unroll")                                                          \
        for (int n_ = 0; n_ < 2; ++n_)                                             \
            _Pragma("unroll")                                                      \
            for (int ks_ = 0; ks_ < 2; ++ks_)                                      \
                bf[(N0) + n_][ks_] = *(const short8*)((BASE) +                     \
                    ((wn * 64 + ((N0) + n_) * 16 + fr) * 128 +                     \
                     ((ks_ * 64 + fk16) ^ sxor)));                                 \
    } while (0)

// one C-quadrant: 4 mi x 2 ni x 2 ks = 16 MFMA
#define MFMAQ(MOFF, NOFF, BOFF)                                                    \
    do {                                                                           \
        _Pragma("unroll")                                                          \
        for (int m_ = 0; m_ < 4; ++m_)                                             \
            _Pragma("unroll")                                                      \
            for (int n_ = 0; n_ < 2; ++n_)                                         \
                _Pragma("unroll")                                                  \
                for (int ks_ = 0; ks_ < 2; ++ks_)                                  \
                    acc[(MOFF) + m_][(NOFF) + n_] =                                \
                        __builtin_amdgcn_mfma_f32_16x16x32_bf16(                   \
                            af[m_][ks_], bf[(BOFF) + n_][ks_],                     \
                            acc[(MOFF) + m_][(NOFF) + n_], 0, 0, 0);               \
    } while (0)

__global__ __launch_bounds__(512, 2) void gemm8(
    const unsigned short* __restrict__ A,
    const unsigned short* __restrict__ B,
    const float* __restrict__ scale,
    const float* __restrict__ bias,
    float* __restrict__ C) {
    __shared__ unsigned short sh[4 * 16384];   // 128 KiB: buf0.A, buf0.B, buf1.A, buf1.B
    unsigned short* A0 = sh;
    unsigned short* B0 = sh + 16384;
    unsigned short* A1 = sh + 32768;
    unsigned short* B1 = sh + 49152;

    const int tid  = threadIdx.x;
    const int lane = tid & 63;
    const int wave = tid >> 6;
    const int wm = wave & 1;     // 2 waves in M (128 rows each)
    const int wn = wave >> 1;    // 4 waves in N (64 cols each)

    // XCD-aware bijective block swizzle: nwg = 32*43 = 1376, 1376 % 8 == 0
    const int cpx = ((M_DIM / TBM) * (N_DIM / TBN)) >> 3;   // 172
    const int wg  = (blockIdx.x & 7) * cpx + (blockIdx.x >> 3);
    const int bm  = wg & 31;     // 32 M-tiles (fast-varying: share B panel)
    const int bn  = wg >> 5;     // 43 N-tiles

    const unsigned short* Apan = A + (size_t)bm * TBM * K_DIM;
    const unsigned short* Bpan = B + (size_t)bn * TBN * K_DIM;

    // staging source offsets: li = iss*512+tid; row=li>>3, chunk=li&7;
    // inverse-swizzle: chunk ^= ((li>>5)&1)<<1  (= row&4 flips 32B pair)
    const int li0 = tid, li1 = tid + 512;
    const size_t so0 = (size_t)(li0 >> 3) * K_DIM +
                       (size_t)((((li0 & 7) ^ (((li0 >> 5) & 1) << 1))) * 8);
    const size_t so1 = (size_t)(li1 >> 3) * K_DIM +
                       (size_t)((((li1 & 7) ^ (((li1 >> 5) & 1) << 1))) * 8);
    const size_t HALF1 = (size_t)128 * K_DIM;   // global row offset of half 1

    // fragment read geometry (16x16x32 bf16): row fr, k-bytes fk16 per k-slice
    const int fr   = lane & 15;
    const int fk16 = (lane >> 4) * 16;
    const int sxor = ((fr >> 2) & 1) << 5;   // st_16x32: (row&4) -> XOR byte bit5

    const char* A0c = (const char*)A0;
    const char* B0c = (const char*)B0;
    const char* A1c = (const char*)A1;
    const char* B1c = (const char*)B1;

    floatx4 acc[8][4] = {};
    short8 af[4][2], bf[4][2];

    // ---- prologue: stage kt0.{A0,A1,B0,B1}, kt1.{B0,B1}; wait kt0 landed ----
    STAGE(Apan,              A0);
    STAGE(Apan + HALF1,      A0 + 8192);
    STAGE(Bpan,              B0);
    STAGE(Bpan + HALF1,      B0 + 8192);
    STAGE(Bpan + 64,         B1);
    STAGE(Bpan + HALF1 + 64, B1 + 8192);
    VM4();     // allow kt1.B (4 issues) outstanding; kt0 fully landed
    BARX();

    // ---- main loop: 32 iterations x (2 K-tiles, 8 phases) ----
    for (int i = 0; i < K_DIM / TBK / 2; ++i) {
        const int kt1 = 2 * i + 1;
        // tail: clamp to 63 -> re-stage same data into already-free regions,
        // keeping issue counts (and vmcnt immediates) exact with no branches
        const int kt2 = (2 * i + 2 < 64) ? 2 * i + 2 : 63;
        const int kt3 = (2 * i + 3 < 64) ? 2 * i + 3 : 63;

        // Phase 1: read af[0-3],bf[0-1] (buf0); stage kt1.A0 -> buf1.A
        LDA4(A0c, 0); LDB2(B0c, 0);
        STAGE(Apan + (size_t)kt1 * 64, A1);
        BARX(); LGKM0(); PHI(); MFMAQ(0, 0, 0); PLO(); BARX();

        // Phase 2: read bf[2-3] (buf0); stage kt1.A1
        LDB2(B0c, 2);
        STAGE(Apan + HALF1 + (size_t)kt1 * 64, A1 + 8192);
        BARX(); LGKM0(); PHI(); MFMAQ(0, 2, 2); PLO(); BARX();

        // Phase 3: read af[4-7] (buf0); stage kt2.B0 -> buf0.B (readers done @Ph2)
        LDA4(A0c, 4);
        STAGE(Bpan + (size_t)kt2 * 64, B0);
        BARX(); LGKM0(); PHI(); MFMAQ(4, 2, 2); PLO(); BARX();

        // Phase 4: stage kt2.B1; counted wait -> kt1 (buf1) fully landed
        STAGE(Bpan + HALF1 + (size_t)kt2 * 64, B0 + 8192);
        VM4();
        BARX(); LGKM0(); PHI(); MFMAQ(4, 0, 0); PLO(); BARX();

        // Phase 5: read af[0-3],bf[0-1] (buf1); stage kt2.A0 -> buf0.A (readers done @Ph3)
        LDA4(A1c, 0); LDB2(B1c, 0);
        STAGE(Apan + (size_t)kt2 * 64, A0);
        BARX(); LGKM0(); PHI(); MFMAQ(0, 0, 0); PLO(); BARX();

        // Phase 6: read bf[2-3] (buf1); stage kt2.A1
        LDB2(B1c, 2);
        STAGE(Apan + HALF1 + (size_t)kt2 * 64, A0 + 8192);
        BARX(); LGKM0(); PHI(); MFMAQ(0, 2, 2); PLO(); BARX();

        // Phase 7: read af[4-7] (buf1); stage kt3.B0 -> buf1.B (readers done @Ph6)
        LDA4(A1c, 4);
        STAGE(Bpan + (size_t)kt3 * 64, B1);
        BARX(); LGKM0(); PHI(); MFMAQ(4, 2, 2); PLO(); BARX();

        // Phase 8: stage kt3.B1; counted wait -> kt2 (buf0) fully landed
        STAGE(Bpan + HALF1 + (size_t)kt3 * 64, B1 + 8192);
        VM4();
        BARX(); LGKM0(); PHI(); MFMAQ(4, 0, 0); PLO(); BARX();
    }

    // ---- epilogue: C/D layout col=lane&15, row=(lane>>4)*4+r; scale+bias ----
    const int cm = (lane >> 4) * 4;
    const int cn = lane & 15;
#pragma unroll
    for (int ni = 0; ni < 4; ++ni) {
        const int gn = bn * TBN + wn * 64 + ni * 16 + cn;
        const float s  = scale[gn];
        const float bb = bias[gn];
#pragma unroll
        for (int mi = 0; mi < 8; ++mi) {
            const int gm0 = bm * TBM + wm * 128 + mi * 16 + cm;
#pragma unroll
            for (int r = 0; r < 4; ++r)
                C[(size_t)(gm0 + r) * N_DIM + gn] = acc[mi][ni][r] * s + bb;
        }
    }
}

// ---- fallback (ws too small): 128x128 register staging + on-the-fly cast ----
__global__ __launch_bounds__(256) void gemm_fused(
    const float* __restrict__ X, const int* __restrict__ W,
    const float* __restrict__ scale, const float* __restrict__ bias,
    float* __restrict__ C) {
    __shared__ unsigned short As[BM * BK];
    __shared__ unsigned short Bs[BN * BK];
    const int tid = threadIdx.x;
    const int lane = tid & 63, wave = tid >> 6;
    const int wm = wave & 1, wn = wave >> 1;
    const int bm = blockIdx.x, bn = blockIdx.y;
    floatx4 acc[4][4] = {};
    const int srow = tid >> 1;
    const int scol = (tid & 1) * 16;
    const float* xp = X + (size_t)(bm * BM + srow) * K_DIM + scol;
    const int*   wp = W + (size_t)(bn * BN + srow) * K_DIM + scol;
    const int fr = lane & 15, fk = (lane >> 4) * 8;

    for (int k0 = 0; k0 < K_DIM; k0 += BK) {
        union { float4 v[4]; float f[16]; } fx;
        union { int4 v[4]; int s[16]; } fw;
#pragma unroll
        for (int i = 0; i < 4; ++i) fx.v[i] = *(const float4*)(xp + k0 + i * 4);
#pragma unroll
        for (int i = 0; i < 4; ++i) fw.v[i] = *(const int4*)(wp + k0 + i * 4);
        union { unsigned short h[16]; uint4 v[2]; } ha, hb;
#pragma unroll
        for (int i = 0; i < 16; ++i) ha.h[i] = f2bf(fx.f[i]);
#pragma unroll
        for (int i = 0; i < 16; ++i) hb.h[i] = f2bf((float)fw.s[i]);
        __syncthreads();
        *(uint4*)(As + srow * BK + scol)     = ha.v[0];
        *(uint4*)(As + srow * BK + scol + 8) = ha.v[1];
        *(uint4*)(Bs + srow * BK + scol)     = hb.v[0];
        *(uint4*)(Bs + srow * BK + scol + 8) = hb.v[1];
        __syncthreads();

        short8 a_f[4], b_f[4];
#pragma unroll
        for (int i = 0; i < 4; ++i)
            a_f[i] = *(const short8*)(As + (wm * 64 + i * 16 + fr) * BK + fk);
#pragma unroll
        for (int i = 0; i < 4; ++i)
            b_f[i] = *(const short8*)(Bs + (wn * 64 + i * 16 + fr) * BK + fk);
#pragma unroll
        for (int mi = 0; mi < 4; ++mi)
#pragma unroll
            for (int ni = 0; ni < 4; ++ni)
                acc[mi][ni] = __builtin_amdgcn_mfma_f32_16x16x32_bf16(
                    a_f[mi], b_f[ni], acc[mi][ni], 0, 0, 0);
    }

    const int cm = (lane >> 4) * 4;
    const int cn = lane & 15;
#pragma unroll
    for (int ni = 0; ni < 4; ++ni) {
        int gn = bn * BN + wn * 64 + ni * 16 + cn;
        float s = scale[gn], bb = bias[gn];
#pragma unroll
        for (int mi = 0; mi < 4; ++mi) {
            int gm0 = bm * BM + wm * 64 + mi * 16 + cm;
#pragma unroll
            for (int r = 0; r < 4; ++r)
                C[(size_t)(gm0 + r) * N_DIM + gn] = acc[mi][ni][r] * s + bb;
        }
    }
}

extern "C" void kernel_launch(void* const* d_in, const int* in_sizes, int n_in,
                              void* d_out, int out_size, void* d_ws, size_t ws_size,
                              hipStream_t stream) {
    const float* x     = (const float*)d_in[0];
    const int*   w     = (const int*)d_in[1];     // int inputs delivered as int32
    const float* scale = (const float*)d_in[2];
    const float* bias  = (const float*)d_in[3];
    float* out = (float*)d_out;

    const size_t a_elems = (size_t)M_DIM * K_DIM;   // 33,554,432
    const size_t b_elems = (size_t)N_DIM * K_DIM;   // 45,088,768
    const size_t need = (a_elems + b_elems) * sizeof(unsigned short);  // ~150 MiB

    if (ws_size >= need) {
        unsigned short* xa = (unsigned short*)d_ws;
        unsigned short* wb = xa + a_elems;
        cvt_x<<<(int)(a_elems / 2048), 256, 0, stream>>>(x, xa);
        cvt_w<<<(int)(b_elems / 2048), 256, 0, stream>>>(w, wb);
        const int nwg = (M_DIM / TBM) * (N_DIM / TBN);   // 1376, % 8 == 0
        gemm8<<<dim3(nwg), dim3(512), 0, stream>>>(xa, wb, scale, bias, out);
    } else {
        dim3 grid(M_DIM / BM, N_DIM / BN);
        gemm_fused<<<grid, 256, 0, stream>>>(x, w, scale, bias, out);
    }
}

// Round 2
// 1158.517 us; speedup vs baseline: 1.3907x; 1.0945x over previous
//
#include <hip/hip_runtime.h>
#include <hip/hip_bf16.h>
#include <stdint.h>

// Int8SymmetricLinear: out[m,n] = sum_k x[m,k] * (int8 W[n,k]) * scale[n] + bias[n]
// M=8192 (B*S), K=4096, N=11008.
// Prepass: x -> bf16 (RTNE), W -> bf16 (exact, |W|<=127).
// Main GEMM: 256x256 8-phase template (m201/m204): BK=64, 8 waves (2Mx4N),
// 128 KiB LDS double-buffer, counted vmcnt(4) at phases 4/8 (never 0 in main
// loop), setprio(1) around MFMA clusters.
// R2 changes vs R1:
//  - T2 fix: 3-bit XOR swizzle slot^=(row&7) (R1's 1-bit st_16x32 left 8-way
//    conflicts: row stride 128B = bank period, so bank = slot only; 1 bit
//    spreads 16 lanes over 2 slots. 3 bits -> 8 slots, 2 lanes/slot = free).
//    Same involution on both sides: inverse-permuted gload_lds SOURCE chunk +
//    XOR'd ds_read column (rule #21).
//  - T1 fix: 4x8 supertile per XCD (172 = 4*43: XCD x owns bm in [4x,4x+4),
//    all 43 bn, bn-major order). R1's 32bm x 1bn co-res set had zero A-sharing
//    -> FETCH 1.5GB. Now K-window working set 384KB << 4MB L2.

#define M_DIM 8192
#define K_DIM 4096
#define N_DIM 11008

// fallback tile (register-staged path)
#define BM 128
#define BN 128
#define BK 32

// 8-phase tile
#define TBM 256
#define TBN 256
#define TBK 64

typedef __attribute__((ext_vector_type(8))) short short8;   // 8 bf16 = 4 VGPRs
typedef __attribute__((ext_vector_type(4))) float floatx4;

__device__ __forceinline__ unsigned short f2bf(float f) {
    __hip_bfloat16 h = __float2bfloat16(f);   // RTNE
    return __builtin_bit_cast(unsigned short, h);
}

// ---- prepass: x fp32 -> bf16 bits (8 elems/thread) ----
__global__ void cvt_x(const float* __restrict__ x, unsigned short* __restrict__ o) {
    int i = (blockIdx.x * 256 + threadIdx.x) * 8;
    float4 a = *(const float4*)(x + i);
    float4 b = *(const float4*)(x + i + 4);
    union { unsigned short h[8]; uint4 v; } u;
    u.h[0] = f2bf(a.x); u.h[1] = f2bf(a.y); u.h[2] = f2bf(a.z); u.h[3] = f2bf(a.w);
    u.h[4] = f2bf(b.x); u.h[5] = f2bf(b.y); u.h[6] = f2bf(b.z); u.h[7] = f2bf(b.w);
    *(uint4*)(o + i) = u.v;
}

// ---- prepass: W int32 (values in [-127,127]) -> bf16 bits (exact) ----
__global__ void cvt_w(const int* __restrict__ w, unsigned short* __restrict__ o) {
    int i = (blockIdx.x * 256 + threadIdx.x) * 8;
    int4 a = *(const int4*)(w + i);
    int4 b = *(const int4*)(w + i + 4);
    union { unsigned short h[8]; uint4 v; } u;
    u.h[0] = f2bf((float)a.x); u.h[1] = f2bf((float)a.y);
    u.h[2] = f2bf((float)a.z); u.h[3] = f2bf((float)a.w);
    u.h[4] = f2bf((float)b.x); u.h[5] = f2bf((float)b.y);
    u.h[6] = f2bf((float)b.z); u.h[7] = f2bf((float)b.w);
    *(uint4*)(o + i) = u.v;
}

// ================= 256x256 8-phase GEMM =================
// LDS layout per K-tile region: 256 rows x 64 bf16 = 128 B/row = 8 slots of
// 16 B. Stored slot s' at (row, s') holds logical slot s = s' ^ (row&7).
// gload_lds writes linearly -> the SOURCE address carries the inverse perm;
// ds_read applies the same XOR on its column slot.

#define BARX()  __builtin_amdgcn_s_barrier()
#define LGKM0() asm volatile("s_waitcnt lgkmcnt(0)" ::: "memory")
#define VM4()   asm volatile("s_waitcnt vmcnt(4)" ::: "memory")
#define PHI()   __builtin_amdgcn_s_setprio(1)
#define PLO()   __builtin_amdgcn_s_setprio(0)

// stage one half-tile (128 rows x 64 cols): 2 x global_load_lds dwordx4 per thread
#define STAGE(GP, LP)                                                              \
    do {                                                                           \
        __builtin_amdgcn_global_load_lds(                                          \
            (const __attribute__((address_space(1))) void*)((GP) + so0),           \
            (__attribute__((address_space(3))) void*)((LP) + tid * 8), 16, 0, 0);  \
        __builtin_amdgcn_global_load_lds(                                          \
            (const __attribute__((address_space(1))) void*)((GP) + so1),           \
            (__attribute__((address_space(3))) void*)((LP) + 4096 + tid * 8), 16, 0, 0); \
    } while (0)

// load 4 A-frags (rows MOFF..MOFF+3 of wave's 8) x 2 k-slices, swizzled ds_read
#define LDA4(BASE, MOFF)                                                           \
    do {                                                                           \
        _Pragma("unroll")                                                          \
        for (int m_ = 0; m_ < 4; ++m_) {                                           \
            const int r_ = (wm * 128 + ((MOFF) + m_) * 16 + fr) * 128;             \
            af[m_][0] = *(const short8*)((BASE) + r_ + col0);                      \
            af[m_][1] = *(const short8*)((BASE) + r_ + col1);                      \
        }                                                                          \
    } while (0)

// load 2 B-frags into bf[N0],bf[N0+1] x 2 k-slices
#define LDB2(BASE, N0)                                                             \
    do {                                                                           \
        _Pragma("unroll")                                                          \
        for (int n_ = 0; n_ < 2; ++n_) {                                           \
            const int r_ = (wn * 64 + ((N0) + n_) * 16 + fr) * 128;                \
            bf[(N0) + n_][0] = *(const short8*)((BASE) + r_ + col0);               \
            bf[(N0) + n_][1] = *(const short8*)((BASE) + r_ + col1);               \
        }                                                                          \
    } while (0)

// one C-quadrant: 4 mi x 2 ni x 2 ks = 16 MFMA
#define MFMAQ(MOFF, NOFF, BOFF)                                                    \
    do {                                                                           \
        _Pragma("unroll")                                                          \
        for (int m_ = 0; m_ < 4; ++m_)                                             \
            _Pragma("unroll")                                                      \
            for (int n_ = 0; n_ < 2; ++n_)                                         \
                _Pragma("unroll")                                                  \
                for (int ks_ = 0; ks_ < 2; ++ks_)                                  \
                    acc[(MOFF) + m_][(NOFF) + n_] =                                \
                        __builtin_amdgcn_mfma_f32_16x16x32_bf16(                   \
                            af[m_][ks_], bf[(BOFF) + n_][ks_],                     \
                            acc[(MOFF) + m_][(NOFF) + n_], 0, 0, 0);               \
    } while (0)

__global__ __launch_bounds__(512, 2) void gemm8(
    const unsigned short* __restrict__ A,
    const unsigned short* __restrict__ B,
    const float* __restrict__ scale,
    const float* __restrict__ bias,
    float* __restrict__ C) {
    __shared__ unsigned short sh[4 * 16384];   // 128 KiB: buf0.A, buf0.B, buf1.A, buf1.B
    unsigned short* A0 = sh;
    unsigned short* B0 = sh + 16384;
    unsigned short* A1 = sh + 32768;
    unsigned short* B1 = sh + 49152;

    const int tid  = threadIdx.x;
    const int lane = tid & 63;
    const int wave = tid >> 6;
    const int wm = wave & 1;     // 2 waves in M (128 rows each)
    const int wn = wave >> 1;    // 4 waves in N (64 cols each)

    // XCD-aware 4x8 supertile: XCD x = bid%8 owns bm in [4x,4x+4), all 43 bn,
    // bn-major -> 32 co-resident blocks form a 4bm x 8bn supertile.
    const int xcd = blockIdx.x & 7;
    const int sq  = blockIdx.x >> 3;        // 0..171 sequential within XCD
    const int bm  = xcd * 4 + (sq & 3);     // 0..31
    const int bn  = sq >> 2;                // 0..42

    const unsigned short* Apan = A + (size_t)bm * TBM * K_DIM;
    const unsigned short* Bpan = B + (size_t)bn * TBN * K_DIM;

    // staging source: li = iss*512+tid; row = li>>3, stored slot = li&7;
    // source chunk = stored_slot ^ (row&7)  (inverse of the read swizzle)
    const int li0 = tid, li1 = tid + 512;
    const size_t so0 = (size_t)(li0 >> 3) * K_DIM +
                       (size_t)(((li0 & 7) ^ ((li0 >> 3) & 7)) * 8);
    const size_t so1 = (size_t)(li1 >> 3) * K_DIM +
                       (size_t)(((li1 & 7) ^ ((li1 >> 3) & 7)) * 8);
    const size_t HALF1 = (size_t)128 * K_DIM;   // global row offset of half 1

    // fragment read geometry (16x16x32 bf16): row fr; column slot for k-slice
    // ks is (ks*4 + (lane>>4)) ^ (row&7); row&7 == fr&7 (16-row frag stride).
    const int fr   = lane & 15;
    const int col0 = (((lane >> 4) ^ (fr & 7)) << 4);   // bytes, ks=0
    const int col1 = col0 ^ 64;                         // ks=1: slot+4 -> XOR 64B

    const char* A0c = (const char*)A0;
    const char* B0c = (const char*)B0;
    const char* A1c = (const char*)A1;
    const char* B1c = (const char*)B1;

    floatx4 acc[8][4] = {};
    short8 af[4][2], bf[4][2];

    // ---- prologue: stage kt0.{A,B both halves}, kt1.{B both halves} ----
    STAGE(Apan,              A0);
    STAGE(Apan + HALF1,      A0 + 8192);
    STAGE(Bpan,              B0);
    STAGE(Bpan + HALF1,      B0 + 8192);
    STAGE(Bpan + 64,         B1);
    STAGE(Bpan + HALF1 + 64, B1 + 8192);
    VM4();     // allow kt1.B (4 issues) outstanding; kt0 fully landed
    BARX();

    // ---- main loop: 32 iterations x (2 K-tiles, 8 phases) ----
    for (int i = 0; i < K_DIM / TBK / 2; ++i) {
        const int kt1 = 2 * i + 1;
        // tail: clamp to 63 -> re-stage same data into already-free regions,
        // keeping issue counts (and vmcnt immediates) exact with no branches
        const int kt2 = (2 * i + 2 < 64) ? 2 * i + 2 : 63;
        const int kt3 = (2 * i + 3 < 64) ? 2 * i + 3 : 63;

        // Phase 1: read af[0-3],bf[0-1] (buf0); stage kt1.A0 -> buf1.A
        LDA4(A0c, 0); LDB2(B0c, 0);
        STAGE(Apan + (size_t)kt1 * 64, A1);
        BARX(); LGKM0(); PHI(); MFMAQ(0, 0, 0); PLO(); BARX();

        // Phase 2: read bf[2-3] (buf0); stage kt1.A1
        LDB2(B0c, 2);
        STAGE(Apan + HALF1 + (size_t)kt1 * 64, A1 + 8192);
        BARX(); LGKM0(); PHI(); MFMAQ(0, 2, 2); PLO(); BARX();

        // Phase 3: read af[4-7] (buf0); stage kt2.B0 -> buf0.B (readers done @Ph2)
        LDA4(A0c, 4);
        STAGE(Bpan + (size_t)kt2 * 64, B0);
        BARX(); LGKM0(); PHI(); MFMAQ(4, 2, 2); PLO(); BARX();

        // Phase 4: stage kt2.B1; counted wait -> kt1 (buf1) fully landed
        STAGE(Bpan + HALF1 + (size_t)kt2 * 64, B0 + 8192);
        VM4();
        BARX(); LGKM0(); PHI(); MFMAQ(4, 0, 0); PLO(); BARX();

        // Phase 5: read af[0-3],bf[0-1] (buf1); stage kt2.A0 -> buf0.A (readers done @Ph3)
        LDA4(A1c, 0); LDB2(B1c, 0);
        STAGE(Apan + (size_t)kt2 * 64, A0);
        BARX(); LGKM0(); PHI(); MFMAQ(0, 0, 0); PLO(); BARX();

        // Phase 6: read bf[2-3] (buf1); stage kt2.A1
        LDB2(B1c, 2);
        STAGE(Apan + HALF1 + (size_t)kt2 * 64, A0 + 8192);
        BARX(); LGKM0(); PHI(); MFMAQ(0, 2, 2); PLO(); BARX();

        // Phase 7: read af[4-7] (buf1); stage kt3.B0 -> buf1.B (readers done @Ph6)
        LDA4(A1c, 4);
        STAGE(Bpan + (size_t)kt3 * 64, B1);
        BARX(); LGKM0(); PHI(); MFMAQ(4, 2, 2); PLO(); BARX();

        // Phase 8: stage kt3.B1; counted wait -> kt2 (buf0) fully landed
        STAGE(Bpan + HALF1 + (size_t)kt3 * 64, B1 + 8192);
        VM4();
        BARX(); LGKM0(); PHI(); MFMAQ(4, 0, 0); PLO(); BARX();
    }

    // ---- epilogue: C/D layout col=lane&15, row=(lane>>4)*4+r; scale+bias ----
    const int cm = (lane >> 4) * 4;
    const int cn = lane & 15;
#pragma unroll
    for (int ni = 0; ni < 4; ++ni) {
        const int gn = bn * TBN + wn * 64 + ni * 16 + cn;
        const float s  = scale[gn];
        const float bb = bias[gn];
#pragma unroll
        for (int mi = 0; mi < 8; ++mi) {
            const int gm0 = bm * TBM + wm * 128 + mi * 16 + cm;
#pragma unroll
            for (int r = 0; r < 4; ++r)
                C[(size_t)(gm0 + r) * N_DIM + gn] = acc[mi][ni][r] * s + bb;
        }
    }
}

// ---- fallback (ws too small): 128x128 register staging + on-the-fly cast ----
__global__ __launch_bounds__(256) void gemm_fused(
    const float* __restrict__ X, const int* __restrict__ W,
    const float* __restrict__ scale, const float* __restrict__ bias,
    float* __restrict__ C) {
    __shared__ unsigned short As[BM * BK];
    __shared__ unsigned short Bs[BN * BK];
    const int tid = threadIdx.x;
    const int lane = tid & 63, wave = tid >> 6;
    const int wm = wave & 1, wn = wave >> 1;
    const int bm = blockIdx.x, bn = blockIdx.y;
    floatx4 acc[4][4] = {};
    const int srow = tid >> 1;
    const int scol = (tid & 1) * 16;
    const float* xp = X + (size_t)(bm * BM + srow) * K_DIM + scol;
    const int*   wp = W + (size_t)(bn * BN + srow) * K_DIM + scol;
    const int fr = lane & 15, fk = (lane >> 4) * 8;

    for (int k0 = 0; k0 < K_DIM; k0 += BK) {
        union { float4 v[4]; float f[16]; } fx;
        union { int4 v[4]; int s[16]; } fw;
#pragma unroll
        for (int i = 0; i < 4; ++i) fx.v[i] = *(const float4*)(xp + k0 + i * 4);
#pragma unroll
        for (int i = 0; i < 4; ++i) fw.v[i] = *(const int4*)(wp + k0 + i * 4);
        union { unsigned short h[16]; uint4 v[2]; } ha, hb;
#pragma unroll
        for (int i = 0; i < 16; ++i) ha.h[i] = f2bf(fx.f[i]);
#pragma unroll
        for (int i = 0; i < 16; ++i) hb.h[i] = f2bf((float)fw.s[i]);
        __syncthreads();
        *(uint4*)(As + srow * BK + scol)     = ha.v[0];
        *(uint4*)(As + srow * BK + scol + 8) = ha.v[1];
        *(uint4*)(Bs + srow * BK + scol)     = hb.v[0];
        *(uint4*)(Bs + srow * BK + scol + 8) = hb.v[1];
        __syncthreads();

        short8 a_f[4], b_f[4];
#pragma unroll
        for (int i = 0; i < 4; ++i)
            a_f[i] = *(const short8*)(As + (wm * 64 + i * 16 + fr) * BK + fk);
#pragma unroll
        for (int i = 0; i < 4; ++i)
            b_f[i] = *(const short8*)(Bs + (wn * 64 + i * 16 + fr) * BK + fk);
#pragma unroll
        for (int mi = 0; mi < 4; ++mi)
#pragma unroll
            for (int ni = 0; ni < 4; ++ni)
                acc[mi][ni] = __builtin_amdgcn_mfma_f32_16x16x32_bf16(
                    a_f[mi], b_f[ni], acc[mi][ni], 0, 0, 0);
    }

    const int cm = (lane >> 4) * 4;
    const int cn = lane & 15;
#pragma unroll
    for (int ni = 0; ni < 4; ++ni) {
        int gn = bn * BN + wn * 64 + ni * 16 + cn;
        float s = scale[gn], bb = bias[gn];
#pragma unroll
        for (int mi = 0; mi < 4; ++mi) {
            int gm0 = bm * BM + wm * 64 + mi * 16 + cm;
#pragma unroll
            for (int r = 0; r < 4; ++r)
                C[(size_t)(gm0 + r) * N_DIM + gn] = acc[mi][ni][r] * s + bb;
        }
    }
}

extern "C" void kernel_launch(void* const* d_in, const int* in_sizes, int n_in,
                              void* d_out, int out_size, void* d_ws, size_t ws_size,
                              hipStream_t stream) {
    const float* x     = (const float*)d_in[0];
    const int*   w     = (const int*)d_in[1];     // int inputs delivered as int32
    const float* scale = (const float*)d_in[2];
    const float* bias  = (const float*)d_in[3];
    float* out = (float*)d_out;

    const size_t a_elems = (size_t)M_DIM * K_DIM;   // 33,554,432
    const size_t b_elems = (size_t)N_DIM * K_DIM;   // 45,088,768
    const size_t need = (a_elems + b_elems) * sizeof(unsigned short);  // ~150 MiB

    if (ws_size >= need) {
        unsigned short* xa = (unsigned short*)d_ws;
        unsigned short* wb = xa + a_elems;
        cvt_x<<<(int)(a_elems / 2048), 256, 0, stream>>>(x, xa);
        cvt_w<<<(int)(b_elems / 2048), 256, 0, stream>>>(w, wb);
        const int nwg = (M_DIM / TBM) * (N_DIM / TBN);   // 1376 = 8 XCDs * 172
        gemm8<<<dim3(nwg), dim3(512), 0, stream>>>(xa, wb, scale, bias, out);
    } else {
        dim3 grid(M_DIM / BM, N_DIM / BN);
        gemm_fused<<<grid, 256, 0, stream>>>(x, w, scale, bias, out);
    }
}